// Round 5
// baseline (193.348 us; speedup 1.0000x reference)
//
#include <hip/hip_runtime.h>
#include <math.h>

// SubGraphTransformer: B=8,N=512,E=256,H=8,HD=32,FF=1024,TOPK=102.
// Floyd-Warshall is dead code: surviving (top-k) entries all have dist==1
// except the diagonal (dist==0); row-constant bias cancels under softmax, so
// only topk bitmask + per-head diagonal delta (emb[1][h]-emb[2][h]) matter.
// R3: all heavy math in bf16 MFMA (16x16x32), fp32 accum/softmax/LN/residual.
// R4: pool split partial+final; pool weights fused into LN2; 1 cvt kernel.
// R5: qkv GEMM writes V transposed [b][h][d][j] -> attention loads K/V frags
// directly from global (no LDS staging, no in-loop barriers); LN1/LN2 fused
// into out-proj/ff2 GEMMs (16x256 full-row blocks, in-register LN).

#define B_ 8
#define N_ 512
#define E_ 256
#define H_ 8
#define HD_ 32
#define TOPK_ 102

typedef __attribute__((ext_vector_type(8))) short bf16x8;
typedef __attribute__((ext_vector_type(4))) float f32x4;

__device__ __forceinline__ unsigned short f2b(float f) {  // fp32->bf16 RNE
  unsigned u = __builtin_bit_cast(unsigned, f);
  return (unsigned short)((u + 0x7FFFu + ((u >> 16) & 1u)) >> 16);
}

// ---------------- 0. fused fp32 -> bf16 cast of x + 4 weight mats ----------------
__global__ __launch_bounds__(256) void cvt_all(
    const float* __restrict__ x, const float* __restrict__ wqkv,
    const float* __restrict__ wout, const float* __restrict__ wff1,
    const float* __restrict__ wff2, unsigned short* __restrict__ xb,
    unsigned short* __restrict__ wqkvb, unsigned short* __restrict__ woutb,
    unsigned short* __restrict__ wff1b, unsigned short* __restrict__ wff2b) {
  int i = (blockIdx.x * 256 + threadIdx.x) * 4;
  const float* src;
  unsigned short* dst;
  int off;
  if (i < 1048576)      { src = x;    dst = xb;    off = i; }
  else if (i < 1245184) { src = wqkv; dst = wqkvb; off = i - 1048576; }
  else if (i < 1310720) { src = wout; dst = woutb; off = i - 1245184; }
  else if (i < 1572864) { src = wff1; dst = wff1b; off = i - 1310720; }
  else                  { src = wff2; dst = wff2b; off = i - 1572864; }
  float4 v = *(const float4*)(src + off);
  ushort4 o;
  o.x = f2b(v.x); o.y = f2b(v.y); o.z = f2b(v.z); o.w = f2b(v.w);
  *(ushort4*)(dst + off) = o;
}

// ---------------- 1. top-k(102) per row -> 512-bit mask ----------------
__global__ __launch_bounds__(256) void topk_kernel(const float* __restrict__ adj,
                                                   unsigned int* __restrict__ bits) {
  const int row = blockIdx.x;  // b*N + i
  const float* a = adj + (size_t)row * N_;
  __shared__ unsigned int hist[1024];
  __shared__ float cval[N_];
  __shared__ int cidx[N_];
  __shared__ int s_cnt;
  __shared__ int s_bb;
  __shared__ int s_need;
  __shared__ unsigned int rowbits[16];
  __shared__ int wsum[4];
  const int t = threadIdx.x;
  const int lane = t & 63;
  const int wave = t >> 6;

  hist[t] = 0u; hist[t + 256] = 0u; hist[t + 512] = 0u; hist[t + 768] = 0u;
  if (t == 0) s_cnt = 0;
  float v0 = a[t];
  float v1 = a[t + 256];
  __syncthreads();
  const int b0 = min(1023, max(0, (int)(v0 * 1024.0f)));
  const int b1 = min(1023, max(0, (int)(v1 * 1024.0f)));
  atomicAdd(&hist[b0], 1u);
  atomicAdd(&hist[b1], 1u);
  __syncthreads();
  const int base = 1020 - 4 * t;
  const int h0 = (int)hist[base], h1 = (int)hist[base + 1];
  const int h2 = (int)hist[base + 2], h3 = (int)hist[base + 3];
  const int g = h0 + h1 + h2 + h3;
  int sc = g;
  #pragma unroll
  for (int off = 1; off < 64; off <<= 1) {
    int y = __shfl_up(sc, off);
    sc += (lane >= off) ? y : 0;
  }
  if (lane == 63) wsum[wave] = sc;
  __syncthreads();
  int wo = 0;
  for (int w = 0; w < wave; w++) wo += wsum[w];
  const int incl = sc + wo;
  const int excl = incl - g;
  if (excl < TOPK_ && incl >= TOPK_) {
    int cum = excl;
    int bb = base;
    const int hh[4] = {h3, h2, h1, h0};
    const int bs[4] = {base + 3, base + 2, base + 1, base};
    #pragma unroll
    for (int u = 0; u < 4; u++) {
      if (cum + hh[u] >= TOPK_) { bb = bs[u]; break; }
      cum += hh[u];
    }
    s_bb = bb;
    s_need = TOPK_ - cum;
  }
  __syncthreads();
  const int bb = s_bb;
  const int need = s_need;
  const bool sel0 = (b0 > bb);
  const bool sel1 = (b1 > bb);
  if (b0 == bb) { int p = atomicAdd(&s_cnt, 1); cval[p] = v0; cidx[p] = t; }
  if (b1 == bb) { int p = atomicAdd(&s_cnt, 1); cval[p] = v1; cidx[p] = t + 256; }
  unsigned long long m0 = __ballot(sel0);
  unsigned long long m1 = __ballot(sel1);
  if (lane == 0) {
    rowbits[2 * wave + 0] = (unsigned int)m0;
    rowbits[2 * wave + 1] = (unsigned int)(m0 >> 32);
    rowbits[8 + 2 * wave + 0] = (unsigned int)m1;
    rowbits[8 + 2 * wave + 1] = (unsigned int)(m1 >> 32);
  }
  __syncthreads();
  const int cnt = s_cnt;
  for (int c = t; c < cnt; c += 256) {
    const float v = cval[c];
    const int idx = cidx[c];
    int r = 0;
    for (int j = 0; j < cnt; j++) {
      const float vj = cval[j];
      const int ij = cidx[j];
      if (vj > v || (vj == v && ij < idx)) r++;
    }
    if (r < need) atomicOr(&rowbits[idx >> 5], 1u << (idx & 31));
  }
  __syncthreads();
  if (t < 16) bits[(size_t)row * 16 + t] = rowbits[t];
}

// ---------------- 2. bf16 MFMA GEMM: C[M,N] = A[M,K]*W[N,K]^T + bias ----------------
// flags: 1=relu, 2=bf16 output. res (fp32) optional.
// vT != nullptr: columns >= 512 (the V part of qkv) are written transposed to
// vT[b][h][d][j] (bf16) instead of row-major Cout.
__global__ __launch_bounds__(256) void gemm_mfma(
    const unsigned short* __restrict__ A, const unsigned short* __restrict__ W,
    const float* __restrict__ bias, const float* __restrict__ res,
    void* __restrict__ Cout, unsigned short* __restrict__ vT,
    int M, int N, int K, int flags) {
  __shared__ __align__(16) unsigned short Af[8 * 64 * 8];  // [mtile*2+kc][lane][8]
  __shared__ __align__(16) unsigned short Wf[8 * 64 * 8];
  const int tid = threadIdx.x;
  const int m0 = blockIdx.y * 64, n0 = blockIdx.x * 64;
  const int wave = tid >> 6, lane = tid & 63;
  const int wm = wave & 1, wn = wave >> 1;
  const int q = lane >> 4, l15 = lane & 15;
  const int r = tid >> 2, c0 = tid & 3;  // staging: row r, chunks c0, c0+4

  f32x4 acc[2][2];
  #pragma unroll
  for (int i = 0; i < 2; i++)
    #pragma unroll
    for (int j = 0; j < 2; j++) acc[i][j] = (f32x4){0.f, 0.f, 0.f, 0.f};

  const size_t arow = (size_t)(m0 + r) * K;
  const size_t wrow = (size_t)(n0 + r) * K;
  for (int k0 = 0; k0 < K; k0 += 64) {
    uint4 a0 = *(const uint4*)(A + arow + k0 + c0 * 8);
    uint4 a1 = *(const uint4*)(A + arow + k0 + (c0 + 4) * 8);
    uint4 w0 = *(const uint4*)(W + wrow + k0 + c0 * 8);
    uint4 w1 = *(const uint4*)(W + wrow + k0 + (c0 + 4) * 8);
    __syncthreads();
    {
      int kc = c0 >> 2, qq = c0 & 3;
      int s0 = ((r >> 4) * 2 + kc) * 64 + (r & 15) + qq * 16;
      int kc1 = (c0 + 4) >> 2, qq1 = (c0 + 4) & 3;
      int s1 = ((r >> 4) * 2 + kc1) * 64 + (r & 15) + qq1 * 16;
      *(uint4*)(Af + s0 * 8) = a0;
      *(uint4*)(Af + s1 * 8) = a1;
      *(uint4*)(Wf + s0 * 8) = w0;
      *(uint4*)(Wf + s1 * 8) = w1;
    }
    __syncthreads();
    #pragma unroll
    for (int kc = 0; kc < 2; kc++) {
      bf16x8 af[2], wf[2];
      #pragma unroll
      for (int mt = 0; mt < 2; mt++)
        af[mt] = *(const bf16x8*)(Af + (((wm * 2 + mt) * 2 + kc) * 64 + lane) * 8);
      #pragma unroll
      for (int nt = 0; nt < 2; nt++)
        wf[nt] = *(const bf16x8*)(Wf + (((wn * 2 + nt) * 2 + kc) * 64 + lane) * 8);
      #pragma unroll
      for (int mt = 0; mt < 2; mt++)
        #pragma unroll
        for (int nt = 0; nt < 2; nt++)
          acc[mt][nt] = __builtin_amdgcn_mfma_f32_16x16x32_bf16(af[mt], wf[nt], acc[mt][nt], 0, 0, 0);
    }
  }
  #pragma unroll
  for (int nt = 0; nt < 2; nt++) {
    const int col = n0 + (wn * 2 + nt) * 16 + l15;
    const float bv = bias[col];
    #pragma unroll
    for (int mt = 0; mt < 2; mt++) {
      const int rowb = m0 + (wm * 2 + mt) * 16 + q * 4;
      float ov[4];
      #pragma unroll
      for (int reg = 0; reg < 4; reg++) {
        float o = acc[mt][nt][reg] + bv;
        if (res) o += res[(size_t)(rowb + reg) * N + col];
        if (flags & 1) o = fmaxf(o, 0.f);
        ov[reg] = o;
      }
      if (vT && col >= 512) {  // uniform per block (n0 multiple of 64)
        const int d = (col - 512) & 31, hh2 = (col - 512) >> 5;
        const int bidx = rowb >> 9, j0 = rowb & 511;
        ushort4 st;
        st.x = f2b(ov[0]); st.y = f2b(ov[1]); st.z = f2b(ov[2]); st.w = f2b(ov[3]);
        *(ushort4*)(vT + ((size_t)((bidx * 8 + hh2) * 32 + d)) * 512 + j0) = st;
      } else {
        #pragma unroll
        for (int reg = 0; reg < 4; reg++) {
          if (flags & 2) ((unsigned short*)Cout)[(size_t)(rowb + reg) * N + col] = f2b(ov[reg]);
          else           ((float*)Cout)[(size_t)(rowb + reg) * N + col] = ov[reg];
        }
      }
    }
  }
}

// ---------------- 3. masked flash attention, bf16 MFMA, barrier-free K-loop ----
// K frags direct from row-major qkv; V frags direct from vT[b][h][d][j].
__global__ __launch_bounds__(256) void attn_mfma(
    const unsigned short* __restrict__ qkv, const unsigned short* __restrict__ vT,
    const unsigned int* __restrict__ bits, const float* __restrict__ emb,
    unsigned short* __restrict__ ctxo) {
  const int bx = blockIdx.x;
  const int ib = bx & 7;
  const int h = (bx >> 3) & 7;
  const int b = bx >> 6;
  const int tid = threadIdx.x;
  const int lane = tid & 63;
  const int wave = tid >> 6;
  const int q = lane >> 4, l15 = lane & 15;

  __shared__ __align__(16) unsigned int mrow[64 * 16];       // mask words, 64 i-rows
  __shared__ __align__(16) unsigned short pF[4][2 * 64 * 8]; // per-wave P A-frags

  {  // stage mask rows once
    int rr = tid >> 2, wq = tid & 3;
    uint4 mw = *(const uint4*)(bits + ((size_t)(b * N_ + ib * 64 + rr)) * 16 + wq * 4);
    *(uint4*)(mrow + rr * 16 + wq * 4) = mw;
  }
  __syncthreads();

  const int i0w = ib * 64 + wave * 16;
  const bf16x8 qf = *(const bf16x8*)(qkv + ((size_t)(b * N_ + i0w + l15)) * 768 + h * HD_ + q * 8);
  const float delta = emb[1 * H_ + h] - emb[2 * H_ + h];
  const float scale = 0.17677669529663687f;  // 1/sqrt(32)

  float m_run[4], l_run[4];
  #pragma unroll
  for (int e = 0; e < 4; e++) { m_run[e] = -1e30f; l_run[e] = 0.f; }
  f32x4 cacc[2];
  cacc[0] = (f32x4){0.f, 0.f, 0.f, 0.f};
  cacc[1] = (f32x4){0.f, 0.f, 0.f, 0.f};

  unsigned short* pbase = &pF[wave][0];
  const unsigned short* kbase = qkv + (size_t)b * N_ * 768 + E_ + h * HD_ + q * 8;
  const unsigned short* vbase = vT + ((size_t)((b * 8 + h) * 32 + l15)) * 512 + q * 8;

  #pragma unroll 1
  for (int jt = 0; jt < 8; jt++) {
    // QK^T: per-lane direct K-frag loads (16B, L2-hot)
    f32x4 s4[4];
    #pragma unroll
    for (int jtile = 0; jtile < 4; jtile++) {
      bf16x8 kf = *(const bf16x8*)(kbase + (size_t)(jt * 64 + jtile * 16 + l15) * 768);
      s4[jtile] = __builtin_amdgcn_mfma_f32_16x16x32_bf16(qf, kf, (f32x4){0.f, 0.f, 0.f, 0.f}, 0, 0, 0);
    }
    unsigned long long mw64[4];
    #pragma unroll
    for (int reg = 0; reg < 4; reg++)
      mw64[reg] = *(const unsigned long long*)(mrow + (wave * 16 + q * 4 + reg) * 16 + jt * 2);
    float smat[4][4];
    #pragma unroll
    for (int jtile = 0; jtile < 4; jtile++) {
      #pragma unroll
      for (int reg = 0; reg < 4; reg++) {
        unsigned int w = (jtile & 2) ? (unsigned int)(mw64[reg] >> 32) : (unsigned int)mw64[reg];
        bool allowed = ((w >> ((jtile & 1) * 16 + l15)) & 1u) != 0u;
        int ig = ib * 64 + wave * 16 + q * 4 + reg;
        int jg = jt * 64 + jtile * 16 + l15;
        float s = s4[jtile][reg] * scale + ((jg == ig) ? delta : 0.f);
        smat[jtile][reg] = allowed ? s : -INFINITY;
      }
    }
    float alpha[4], pmat[4][4];
    #pragma unroll
    for (int reg = 0; reg < 4; reg++) {
      float mloc = fmaxf(fmaxf(smat[0][reg], smat[1][reg]), fmaxf(smat[2][reg], smat[3][reg]));
      #pragma unroll
      for (int off = 1; off < 16; off <<= 1) mloc = fmaxf(mloc, __shfl_xor(mloc, off));
      float mnew = fmaxf(m_run[reg], mloc);
      alpha[reg] = __expf(m_run[reg] - mnew);
      m_run[reg] = mnew;
      float ps = 0.f;
      #pragma unroll
      for (int jtile = 0; jtile < 4; jtile++) {
        float p = __expf(smat[jtile][reg] - mnew);
        pmat[jtile][reg] = p;
        ps += p;
      }
      #pragma unroll
      for (int off = 1; off < 16; off <<= 1) ps += __shfl_xor(ps, off);
      l_run[reg] = l_run[reg] * alpha[reg] + ps;
      cacc[0][reg] *= alpha[reg];
      cacc[1][reg] *= alpha[reg];
    }
    // P -> LDS (A-frag order, per-wave region; same-wave RAW, no barrier)
    #pragma unroll
    for (int jtile = 0; jtile < 4; jtile++) {
      int j_l = jtile * 16 + l15;
      int sl = ((j_l >> 5) * 64 + ((j_l >> 3) & 3) * 16) * 8 + (j_l & 7);
      #pragma unroll
      for (int reg = 0; reg < 4; reg++)
        pbase[sl + (q * 4 + reg) * 8] = f2b(pmat[jtile][reg]);
    }
    // PV: per-lane direct V-frag loads from vT
    #pragma unroll
    for (int kc = 0; kc < 2; kc++) {
      bf16x8 pf = *(const bf16x8*)(pbase + (kc * 64 + lane) * 8);
      #pragma unroll
      for (int dt = 0; dt < 2; dt++) {
        bf16x8 vf = *(const bf16x8*)(vbase + (size_t)dt * 16 * 512 + jt * 64 + kc * 32);
        cacc[dt] = __builtin_amdgcn_mfma_f32_16x16x32_bf16(pf, vf, cacc[dt], 0, 0, 0);
      }
    }
  }
  #pragma unroll
  for (int reg = 0; reg < 4; reg++) {
    const float linv = 1.f / l_run[reg];
    const size_t row = (size_t)(b * N_ + i0w + q * 4 + reg);
    #pragma unroll
    for (int dt = 0; dt < 2; dt++)
      ctxo[row * E_ + h * HD_ + dt * 16 + l15] = f2b(cacc[dt][reg] * linv);
  }
}

// ---------------- 4. fused GEMM (full-row) + residual + LayerNorm ----------------
// C[M,256] = A[M,K]*W[256,K]^T + bias + res; LN over 256 cols; fp32 out +
// optional bf16 out; optional pooling weight ew[row]=exp(tanh(dot(o,wp)+bp)).
// grid M/16 blocks; block = 4 waves; wave w owns cols w*64..w*64+63, rows 0..15.
// Frags loaded per-lane directly from global (16B, L2-hot) — no staging LDS.
__global__ __launch_bounds__(256) void gemm_ln(
    const unsigned short* __restrict__ A, const unsigned short* __restrict__ W,
    const float* __restrict__ bias, const float* __restrict__ res,
    const float* __restrict__ g, const float* __restrict__ be,
    float* __restrict__ xout, unsigned short* __restrict__ xbout,
    const float* __restrict__ wp, const float* __restrict__ bp,
    float* __restrict__ ew, int K) {
  const int tid = threadIdx.x;
  const int wv = tid >> 6, lane = tid & 63;
  const int q = lane >> 4, l15 = lane & 15;
  const int m0 = blockIdx.x * 16;
  f32x4 acc[4];
  #pragma unroll
  for (int nt = 0; nt < 4; nt++) acc[nt] = (f32x4){0.f, 0.f, 0.f, 0.f};

  const unsigned short* ap = A + (size_t)(m0 + l15) * K + q * 8;
  const unsigned short* wr = W + (size_t)(wv * 64 + l15) * K + q * 8;
  const int K32 = K >> 5;
  for (int kc = 0; kc < K32; kc++) {
    bf16x8 af = *(const bf16x8*)(ap + kc * 32);
    #pragma unroll
    for (int nt = 0; nt < 4; nt++) {
      bf16x8 wf = *(const bf16x8*)(wr + (size_t)nt * 16 * K + kc * 32);
      acc[nt] = __builtin_amdgcn_mfma_f32_16x16x32_bf16(af, wf, acc[nt], 0, 0, 0);
    }
  }
  __shared__ float rs[16][4], rs2[16][4];
  float o[4][4];
  int cols[4];
  #pragma unroll
  for (int nt = 0; nt < 4; nt++) cols[nt] = wv * 64 + nt * 16 + l15;
  #pragma unroll
  for (int reg = 0; reg < 4; reg++) {
    const int row = m0 + q * 4 + reg;
    float p = 0.f, p2 = 0.f;
    #pragma unroll
    for (int nt = 0; nt < 4; nt++) {
      float v = acc[nt][reg] + bias[cols[nt]];
      if (res) v += res[(size_t)row * 256 + cols[nt]];
      o[nt][reg] = v;
      p += v; p2 += v * v;
    }
    #pragma unroll
    for (int off = 1; off < 16; off <<= 1) {  // reduce within 16-lane group
      p += __shfl_xor(p, off);
      p2 += __shfl_xor(p2, off);
    }
    if (l15 == 0) { rs[q * 4 + reg][wv] = p; rs2[q * 4 + reg][wv] = p2; }
  }
  __syncthreads();
  #pragma unroll
  for (int reg = 0; reg < 4; reg++) {
    const int r = q * 4 + reg;
    float s = rs[r][0] + rs[r][1] + rs[r][2] + rs[r][3];
    float s2 = rs2[r][0] + rs2[r][1] + rs2[r][2] + rs2[r][3];
    float mean = s * (1.f / 256.f);
    float var = s2 * (1.f / 256.f) - mean * mean;
    float inv = rsqrtf(var + 1e-5f);
    #pragma unroll
    for (int nt = 0; nt < 4; nt++) {
      float on = (o[nt][reg] - mean) * inv * g[cols[nt]] + be[cols[nt]];
      o[nt][reg] = on;
      xout[(size_t)(m0 + r) * 256 + cols[nt]] = on;
      if (xbout) xbout[(size_t)(m0 + r) * 256 + cols[nt]] = f2b(on);
    }
  }
  if (ew) {
    __syncthreads();
    #pragma unroll
    for (int reg = 0; reg < 4; reg++) {
      float d = 0.f;
      #pragma unroll
      for (int nt = 0; nt < 4; nt++) d += o[nt][reg] * wp[cols[nt]];
      #pragma unroll
      for (int off = 1; off < 16; off <<= 1) d += __shfl_xor(d, off);
      if (l15 == 0) rs[q * 4 + reg][wv] = d;
    }
    __syncthreads();
    if (wv == 0 && l15 == 0) {
      #pragma unroll
      for (int reg = 0; reg < 4; reg++) {
        const int r = q * 4 + reg;
        float dot = rs[r][0] + rs[r][1] + rs[r][2] + rs[r][3] + bp[0];
        ew[m0 + r] = __expf(tanhf(dot));
      }
    }
  }
}

// ---------------- 5a. pooling partial sums: 32 chunks x 8 batches ----------------
__global__ __launch_bounds__(256) void pool_partial(
    const float* __restrict__ x2, const float* __restrict__ ew,
    float* __restrict__ partial, float* __restrict__ pwsum) {
  const int c = blockIdx.x;   // 0..31
  const int b = blockIdx.y;   // 0..7
  const int tid = threadIdx.x;
  const int r0 = b * N_ + c * 16;
  float acc = 0.f;
  #pragma unroll
  for (int n = 0; n < 16; n++)
    acc += ew[r0 + n] * x2[(size_t)(r0 + n) * E_ + tid];
  partial[(size_t)(b * 32 + c) * E_ + tid] = acc;
  if (tid < 16) {
    float w = ew[r0 + tid];
    #pragma unroll
    for (int off = 1; off < 16; off <<= 1) w += __shfl_xor(w, off);
    if (tid == 0) pwsum[b * 32 + c] = w;
  }
}

// ---------------- 5b. pooling final reduce ----------------
__global__ __launch_bounds__(256) void pool_final(
    const float* __restrict__ partial, const float* __restrict__ pwsum,
    float* __restrict__ out) {
  const int b = blockIdx.x;
  const int tid = threadIdx.x;
  float acc = 0.f, ws = 0.f;
  #pragma unroll
  for (int c = 0; c < 32; c++) acc += partial[(size_t)(b * 32 + c) * E_ + tid];
  #pragma unroll
  for (int c = 0; c < 32; c++) ws += pwsum[b * 32 + c];
  out[b * E_ + tid] = acc / ws;
}

// ---------------- launch ----------------
extern "C" void kernel_launch(void* const* d_in, const int* in_sizes, int n_in,
                              void* d_out, int out_size, void* d_ws, size_t ws_size,
                              hipStream_t stream) {
  (void)in_sizes; (void)n_in; (void)out_size; (void)ws_size;
  const float* x      = (const float*)d_in[0];
  const float* adj    = (const float*)d_in[1];
  const float* emb    = (const float*)d_in[2];
  const float* w_qkv  = (const float*)d_in[3];
  const float* b_qkv  = (const float*)d_in[4];
  const float* w_out  = (const float*)d_in[5];
  const float* b_out  = (const float*)d_in[6];
  const float* w_ff1  = (const float*)d_in[7];
  const float* b_ff1  = (const float*)d_in[8];
  const float* w_ff2  = (const float*)d_in[9];
  const float* b_ff2  = (const float*)d_in[10];
  const float* g1     = (const float*)d_in[11];
  const float* be1    = (const float*)d_in[12];
  const float* g2     = (const float*)d_in[13];
  const float* be2    = (const float*)d_in[14];
  const float* w_pool = (const float*)d_in[15];
  const float* b_pool = (const float*)d_in[16];

  char* ws = (char*)d_ws;
  unsigned int*   bits  = (unsigned int*)ws;                       // 256 KB
  unsigned short* xb    = (unsigned short*)(ws + 262144);          // 2 MB
  unsigned short* qkvb  = (unsigned short*)(ws + 2359296);         // 6 MB (q,k rows; V cols skipped)
  unsigned short* hffb  = xb;                                      // 8 MB reuse (qkvb dead by ff1)
  unsigned short* ctxb  = (unsigned short*)(ws + 8650752);         // 2 MB
  unsigned short* x1b   = (unsigned short*)(ws + 10747904);        // 2 MB
  unsigned short* wqkvb = (unsigned short*)(ws + 12845056);        // 384 KB
  unsigned short* woutb = (unsigned short*)(ws + 13238272);        // 128 KB
  unsigned short* wff1b = (unsigned short*)(ws + 13369344);        // 512 KB
  unsigned short* wff2b = (unsigned short*)(ws + 13893632);        // 512 KB
  unsigned short* vTb   = (unsigned short*)(ws + 14417920);        // 2 MB [b][h][d][j]
  float*          x1    = (float*)(ws + 18612224);                 // 4 MB
  float*          x2    = (float*)(ws + 22806528);                 // 4 MB
  // pooling scratch reuses ctxb region (dead after out-proj gemm)
  float*          ew      = (float*)(ws + 8650752);                // 16 KB
  float*          partial = (float*)(ws + 8650752 + 16384);        // 256 KB
  float*          pwsum   = (float*)(ws + 8650752 + 16384 + 262144);
  float*          outp  = (float*)d_out;

  const int M = B_ * N_;  // 4096

  cvt_all<<<1835008 / 1024, 256, 0, stream>>>(x, w_qkv, w_out, w_ff1, w_ff2,
                                              xb, wqkvb, woutb, wff1b, wff2b);
  topk_kernel<<<B_ * N_, 256, 0, stream>>>(adj, bits);
  gemm_mfma<<<dim3(768 / 64, M / 64), 256, 0, stream>>>(
      xb, wqkvb, b_qkv, nullptr, qkvb, vTb, M, 768, E_, 2);
  attn_mfma<<<B_ * H_ * (N_ / 64), 256, 0, stream>>>(qkvb, vTb, bits, emb, ctxb);
  gemm_ln<<<M / 16, 256, 0, stream>>>(ctxb, woutb, b_out, x, g1, be1,
                                      x1, x1b, nullptr, nullptr, nullptr, E_);
  gemm_mfma<<<dim3(1024 / 64, M / 64), 256, 0, stream>>>(
      x1b, wff1b, b_ff1, nullptr, hffb, nullptr, M, 1024, E_, 1 | 2);
  gemm_ln<<<M / 16, 256, 0, stream>>>(hffb, wff2b, b_ff2, x1, g2, be2,
                                      x2, nullptr, w_pool, b_pool, ew, 1024);
  pool_partial<<<dim3(32, 8), 256, 0, stream>>>(x2, ew, partial, pwsum);
  pool_final<<<B_, 256, 0, stream>>>(partial, pwsum, outp);
}

// Round 6
// 177.459 us; speedup vs baseline: 1.0895x; 1.0895x over previous
//
#include <hip/hip_runtime.h>
#include <math.h>

// SubGraphTransformer: B=8,N=512,E=256,H=8,HD=32,FF=1024,TOPK=102.
// Floyd-Warshall is dead code: surviving (top-k) entries all have dist==1
// except the diagonal (dist==0); row-constant bias cancels under softmax, so
// only topk bitmask + per-head diagonal delta (emb[1][h]-emb[2][h]) matter.
// R3: heavy math in bf16 MFMA (16x16x32), fp32 accum/softmax/LN/residual.
// R4: pool split partial+final; pool weights fused into LN2; 1 cvt kernel.
// R5 (regressed, reverted): direct uncoalesced frag gathers (stride 1.5KB).
// R6: qkv GEMM epilogue writes K,V in MFMA-frag-order global layouts kG/vG
// -> attn frag loads are base+lane*16 (fully coalesced), no K/V LDS, no
// in-loop barriers. LN fusion reverted to R4's gemm_mfma + layernorm.

#define B_ 8
#define N_ 512
#define E_ 256
#define H_ 8
#define HD_ 32
#define TOPK_ 102

typedef __attribute__((ext_vector_type(8))) short bf16x8;
typedef __attribute__((ext_vector_type(4))) float f32x4;

__device__ __forceinline__ unsigned short f2b(float f) {  // fp32->bf16 RNE
  unsigned u = __builtin_bit_cast(unsigned, f);
  return (unsigned short)((u + 0x7FFFu + ((u >> 16) & 1u)) >> 16);
}

// ---------------- 0. fused fp32 -> bf16 cast of x + 4 weight mats ----------------
__global__ __launch_bounds__(256) void cvt_all(
    const float* __restrict__ x, const float* __restrict__ wqkv,
    const float* __restrict__ wout, const float* __restrict__ wff1,
    const float* __restrict__ wff2, unsigned short* __restrict__ xb,
    unsigned short* __restrict__ wqkvb, unsigned short* __restrict__ woutb,
    unsigned short* __restrict__ wff1b, unsigned short* __restrict__ wff2b) {
  int i = (blockIdx.x * 256 + threadIdx.x) * 4;
  const float* src;
  unsigned short* dst;
  int off;
  if (i < 1048576)      { src = x;    dst = xb;    off = i; }
  else if (i < 1245184) { src = wqkv; dst = wqkvb; off = i - 1048576; }
  else if (i < 1310720) { src = wout; dst = woutb; off = i - 1245184; }
  else if (i < 1572864) { src = wff1; dst = wff1b; off = i - 1310720; }
  else                  { src = wff2; dst = wff2b; off = i - 1572864; }
  float4 v = *(const float4*)(src + off);
  ushort4 o;
  o.x = f2b(v.x); o.y = f2b(v.y); o.z = f2b(v.z); o.w = f2b(v.w);
  *(ushort4*)(dst + off) = o;
}

// ---------------- 1. top-k(102) per row -> 512-bit mask ----------------
__global__ __launch_bounds__(256) void topk_kernel(const float* __restrict__ adj,
                                                   unsigned int* __restrict__ bits) {
  const int row = blockIdx.x;  // b*N + i
  const float* a = adj + (size_t)row * N_;
  __shared__ unsigned int hist[1024];
  __shared__ float cval[N_];
  __shared__ int cidx[N_];
  __shared__ int s_cnt;
  __shared__ int s_bb;
  __shared__ int s_need;
  __shared__ unsigned int rowbits[16];
  __shared__ int wsum[4];
  const int t = threadIdx.x;
  const int lane = t & 63;
  const int wave = t >> 6;

  hist[t] = 0u; hist[t + 256] = 0u; hist[t + 512] = 0u; hist[t + 768] = 0u;
  if (t == 0) s_cnt = 0;
  float v0 = a[t];
  float v1 = a[t + 256];
  __syncthreads();
  const int b0 = min(1023, max(0, (int)(v0 * 1024.0f)));
  const int b1 = min(1023, max(0, (int)(v1 * 1024.0f)));
  atomicAdd(&hist[b0], 1u);
  atomicAdd(&hist[b1], 1u);
  __syncthreads();
  const int base = 1020 - 4 * t;
  const int h0 = (int)hist[base], h1 = (int)hist[base + 1];
  const int h2 = (int)hist[base + 2], h3 = (int)hist[base + 3];
  const int g = h0 + h1 + h2 + h3;
  int sc = g;
  #pragma unroll
  for (int off = 1; off < 64; off <<= 1) {
    int y = __shfl_up(sc, off);
    sc += (lane >= off) ? y : 0;
  }
  if (lane == 63) wsum[wave] = sc;
  __syncthreads();
  int wo = 0;
  for (int w = 0; w < wave; w++) wo += wsum[w];
  const int incl = sc + wo;
  const int excl = incl - g;
  if (excl < TOPK_ && incl >= TOPK_) {
    int cum = excl;
    int bb = base;
    const int hh[4] = {h3, h2, h1, h0};
    const int bs[4] = {base + 3, base + 2, base + 1, base};
    #pragma unroll
    for (int u = 0; u < 4; u++) {
      if (cum + hh[u] >= TOPK_) { bb = bs[u]; break; }
      cum += hh[u];
    }
    s_bb = bb;
    s_need = TOPK_ - cum;
  }
  __syncthreads();
  const int bb = s_bb;
  const int need = s_need;
  const bool sel0 = (b0 > bb);
  const bool sel1 = (b1 > bb);
  if (b0 == bb) { int p = atomicAdd(&s_cnt, 1); cval[p] = v0; cidx[p] = t; }
  if (b1 == bb) { int p = atomicAdd(&s_cnt, 1); cval[p] = v1; cidx[p] = t + 256; }
  unsigned long long m0 = __ballot(sel0);
  unsigned long long m1 = __ballot(sel1);
  if (lane == 0) {
    rowbits[2 * wave + 0] = (unsigned int)m0;
    rowbits[2 * wave + 1] = (unsigned int)(m0 >> 32);
    rowbits[8 + 2 * wave + 0] = (unsigned int)m1;
    rowbits[8 + 2 * wave + 1] = (unsigned int)(m1 >> 32);
  }
  __syncthreads();
  const int cnt = s_cnt;
  for (int c = t; c < cnt; c += 256) {
    const float v = cval[c];
    const int idx = cidx[c];
    int r = 0;
    for (int j = 0; j < cnt; j++) {
      const float vj = cval[j];
      const int ij = cidx[j];
      if (vj > v || (vj == v && ij < idx)) r++;
    }
    if (r < need) atomicOr(&rowbits[idx >> 5], 1u << (idx & 31));
  }
  __syncthreads();
  if (t < 16) bits[(size_t)row * 16 + t] = rowbits[t];
}

// ---------------- 2. bf16 MFMA GEMM: C[M,N] = A[M,K]*W[N,K]^T + bias ----------------
// flags: 1=relu, 2=bf16 output. res (fp32) optional.
// kG/vG != nullptr (qkv mode): cols [256,512) -> kG frag-order; cols [512,768)
// -> vG frag-order; cols [0,256) row-major Cout.
// kG/vG layout: [b][h][jt(8)][frag(4)][lane(64)][8 shorts]:
//   kG frag=jtile: lane=q*16+l15 holds K[j=jt*64+jtile*16+l15][d=q*8+sub]
//   vG frag=dt*2+kc: lane=q*16+l15 holds V[d=dt*16+l15][j=jt*64+kc*32+q*8+sub]
__global__ __launch_bounds__(256) void gemm_mfma(
    const unsigned short* __restrict__ A, const unsigned short* __restrict__ W,
    const float* __restrict__ bias, const float* __restrict__ res,
    void* __restrict__ Cout, unsigned short* __restrict__ kG,
    unsigned short* __restrict__ vG, int M, int N, int K, int flags) {
  __shared__ __align__(16) unsigned short Af[8 * 64 * 8];  // [mtile*2+kc][lane][8]
  __shared__ __align__(16) unsigned short Wf[8 * 64 * 8];
  const int tid = threadIdx.x;
  const int m0 = blockIdx.y * 64, n0 = blockIdx.x * 64;
  const int wave = tid >> 6, lane = tid & 63;
  const int wm = wave & 1, wn = wave >> 1;
  const int q = lane >> 4, l15 = lane & 15;
  const int r = tid >> 2, c0 = tid & 3;  // staging: row r, chunks c0, c0+4

  f32x4 acc[2][2];
  #pragma unroll
  for (int i = 0; i < 2; i++)
    #pragma unroll
    for (int j = 0; j < 2; j++) acc[i][j] = (f32x4){0.f, 0.f, 0.f, 0.f};

  const size_t arow = (size_t)(m0 + r) * K;
  const size_t wrow = (size_t)(n0 + r) * K;
  for (int k0 = 0; k0 < K; k0 += 64) {
    uint4 a0 = *(const uint4*)(A + arow + k0 + c0 * 8);
    uint4 a1 = *(const uint4*)(A + arow + k0 + (c0 + 4) * 8);
    uint4 w0 = *(const uint4*)(W + wrow + k0 + c0 * 8);
    uint4 w1 = *(const uint4*)(W + wrow + k0 + (c0 + 4) * 8);
    __syncthreads();
    {
      int kc = c0 >> 2, qq = c0 & 3;
      int s0 = ((r >> 4) * 2 + kc) * 64 + (r & 15) + qq * 16;
      int kc1 = (c0 + 4) >> 2, qq1 = (c0 + 4) & 3;
      int s1 = ((r >> 4) * 2 + kc1) * 64 + (r & 15) + qq1 * 16;
      *(uint4*)(Af + s0 * 8) = a0;
      *(uint4*)(Af + s1 * 8) = a1;
      *(uint4*)(Wf + s0 * 8) = w0;
      *(uint4*)(Wf + s1 * 8) = w1;
    }
    __syncthreads();
    #pragma unroll
    for (int kc = 0; kc < 2; kc++) {
      bf16x8 af[2], wf[2];
      #pragma unroll
      for (int mt = 0; mt < 2; mt++)
        af[mt] = *(const bf16x8*)(Af + (((wm * 2 + mt) * 2 + kc) * 64 + lane) * 8);
      #pragma unroll
      for (int nt = 0; nt < 2; nt++)
        wf[nt] = *(const bf16x8*)(Wf + (((wn * 2 + nt) * 2 + kc) * 64 + lane) * 8);
      #pragma unroll
      for (int mt = 0; mt < 2; mt++)
        #pragma unroll
        for (int nt = 0; nt < 2; nt++)
          acc[mt][nt] = __builtin_amdgcn_mfma_f32_16x16x32_bf16(af[mt], wf[nt], acc[mt][nt], 0, 0, 0);
    }
  }
  #pragma unroll
  for (int nt = 0; nt < 2; nt++) {
    const int col = n0 + (wn * 2 + nt) * 16 + l15;
    const float bv = bias[col];
    #pragma unroll
    for (int mt = 0; mt < 2; mt++) {
      const int rowb = m0 + (wm * 2 + mt) * 16 + q * 4;
      float ov[4];
      #pragma unroll
      for (int reg = 0; reg < 4; reg++) {
        float o = acc[mt][nt][reg] + bv;
        if (res) o += res[(size_t)(rowb + reg) * N + col];
        if (flags & 1) o = fmaxf(o, 0.f);
        ov[reg] = o;
      }
      if (kG && col >= 256 && col < 512) {        // K -> frag-order (scalar u16 x4)
        const int dfull = col - 256;
        const int hh2 = dfull >> 5, d = dfull & 31;
        const int q2 = d >> 3, sub = d & 7;
        const int bidx = rowb >> 9, j = rowb & 511;
        const int jt = j >> 6, jtile = (j >> 4) & 3, jl = j & 15;
        unsigned short* kp = kG +
            ((size_t)(((bidx * 8 + hh2) * 8 + jt) * 4 + jtile) * 64 + q2 * 16 + jl) * 8 + sub;
        kp[0] = f2b(ov[0]); kp[8] = f2b(ov[1]); kp[16] = f2b(ov[2]); kp[24] = f2b(ov[3]);
      } else if (vG && col >= 512) {              // V -> frag-order (ushort4)
        const int dfull = col - 512;
        const int hh2 = dfull >> 5, d = dfull & 31;
        const int dt = d >> 4, dl = d & 15;
        const int bidx = rowb >> 9, j = rowb & 511;
        const int jt = j >> 6, jj = j & 63;
        const int kc = jj >> 5, q2 = (jj >> 3) & 3, sub0 = jj & 7;
        ushort4 st;
        st.x = f2b(ov[0]); st.y = f2b(ov[1]); st.z = f2b(ov[2]); st.w = f2b(ov[3]);
        *(ushort4*)(vG +
            ((size_t)(((bidx * 8 + hh2) * 8 + jt) * 4 + dt * 2 + kc) * 64 + q2 * 16 + dl) * 8 + sub0) = st;
      } else {
        #pragma unroll
        for (int reg = 0; reg < 4; reg++) {
          if (flags & 2) ((unsigned short*)Cout)[(size_t)(rowb + reg) * N + col] = f2b(ov[reg]);
          else           ((float*)Cout)[(size_t)(rowb + reg) * N + col] = ov[reg];
        }
      }
    }
  }
}

// ---------------- 3. masked flash attention, bf16 MFMA ----------------
// All K/V frag loads coalesced (base + lane*16) from frag-order kG/vG.
// No K/V LDS, no in-loop barriers (pF is per-wave).
__global__ __launch_bounds__(256) void attn_mfma(
    const unsigned short* __restrict__ qkv, const unsigned short* __restrict__ kG,
    const unsigned short* __restrict__ vG, const unsigned int* __restrict__ bits,
    const float* __restrict__ emb, unsigned short* __restrict__ ctxo) {
  const int bx = blockIdx.x;
  const int ib = bx & 7;
  const int h = (bx >> 3) & 7;
  const int b = bx >> 6;
  const int tid = threadIdx.x;
  const int lane = tid & 63;
  const int wave = tid >> 6;
  const int q = lane >> 4, l15 = lane & 15;

  __shared__ __align__(16) unsigned int mrow[64 * 16];       // mask words, 64 i-rows
  __shared__ __align__(16) unsigned short pF[4][2 * 64 * 8]; // per-wave P A-frags

  {  // stage mask rows once
    int rr = tid >> 2, wq = tid & 3;
    uint4 mw = *(const uint4*)(bits + ((size_t)(b * N_ + ib * 64 + rr)) * 16 + wq * 4);
    *(uint4*)(mrow + rr * 16 + wq * 4) = mw;
  }
  __syncthreads();

  const int i0w = ib * 64 + wave * 16;
  const bf16x8 qf = *(const bf16x8*)(qkv + ((size_t)(b * N_ + i0w + l15)) * 768 + h * HD_ + q * 8);
  const float delta = emb[1 * H_ + h] - emb[2 * H_ + h];
  const float scale = 0.17677669529663687f;  // 1/sqrt(32)

  float m_run[4], l_run[4];
  #pragma unroll
  for (int e = 0; e < 4; e++) { m_run[e] = -1e30f; l_run[e] = 0.f; }
  f32x4 cacc[2];
  cacc[0] = (f32x4){0.f, 0.f, 0.f, 0.f};
  cacc[1] = (f32x4){0.f, 0.f, 0.f, 0.f};

  unsigned short* pbase = &pF[wave][0];
  const unsigned short* kb = kG + (size_t)(b * 8 + h) * 8 * 4 * 512;
  const unsigned short* vb = vG + (size_t)(b * 8 + h) * 8 * 4 * 512;

  #pragma unroll 1
  for (int jt = 0; jt < 8; jt++) {
    // QK^T: coalesced frag loads (1KB/wave-instruction, L2-hot)
    f32x4 s4[4];
    #pragma unroll
    for (int jtile = 0; jtile < 4; jtile++) {
      bf16x8 kf = *(const bf16x8*)(kb + (size_t)(jt * 4 + jtile) * 512 + lane * 8);
      s4[jtile] = __builtin_amdgcn_mfma_f32_16x16x32_bf16(qf, kf, (f32x4){0.f, 0.f, 0.f, 0.f}, 0, 0, 0);
    }
    unsigned long long mw64[4];
    #pragma unroll
    for (int reg = 0; reg < 4; reg++)
      mw64[reg] = *(const unsigned long long*)(mrow + (wave * 16 + q * 4 + reg) * 16 + jt * 2);
    float smat[4][4];
    #pragma unroll
    for (int jtile = 0; jtile < 4; jtile++) {
      #pragma unroll
      for (int reg = 0; reg < 4; reg++) {
        unsigned int w = (jtile & 2) ? (unsigned int)(mw64[reg] >> 32) : (unsigned int)mw64[reg];
        bool allowed = ((w >> ((jtile & 1) * 16 + l15)) & 1u) != 0u;
        int ig = ib * 64 + wave * 16 + q * 4 + reg;
        int jg = jt * 64 + jtile * 16 + l15;
        float s = s4[jtile][reg] * scale + ((jg == ig) ? delta : 0.f);
        smat[jtile][reg] = allowed ? s : -INFINITY;
      }
    }
    float alpha[4], pmat[4][4];
    #pragma unroll
    for (int reg = 0; reg < 4; reg++) {
      float mloc = fmaxf(fmaxf(smat[0][reg], smat[1][reg]), fmaxf(smat[2][reg], smat[3][reg]));
      #pragma unroll
      for (int off = 1; off < 16; off <<= 1) mloc = fmaxf(mloc, __shfl_xor(mloc, off));
      float mnew = fmaxf(m_run[reg], mloc);
      alpha[reg] = __expf(m_run[reg] - mnew);
      m_run[reg] = mnew;
      float ps = 0.f;
      #pragma unroll
      for (int jtile = 0; jtile < 4; jtile++) {
        float p = __expf(smat[jtile][reg] - mnew);
        pmat[jtile][reg] = p;
        ps += p;
      }
      #pragma unroll
      for (int off = 1; off < 16; off <<= 1) ps += __shfl_xor(ps, off);
      l_run[reg] = l_run[reg] * alpha[reg] + ps;
      cacc[0][reg] *= alpha[reg];
      cacc[1][reg] *= alpha[reg];
    }
    // P -> LDS (A-frag order, per-wave region; same-wave RAW, no barrier)
    #pragma unroll
    for (int jtile = 0; jtile < 4; jtile++) {
      int j_l = jtile * 16 + l15;
      int sl = ((j_l >> 5) * 64 + ((j_l >> 3) & 3) * 16) * 8 + (j_l & 7);
      #pragma unroll
      for (int reg = 0; reg < 4; reg++)
        pbase[sl + (q * 4 + reg) * 8] = f2b(pmat[jtile][reg]);
    }
    // PV: coalesced V frag loads
    #pragma unroll
    for (int kc = 0; kc < 2; kc++) {
      bf16x8 pf = *(const bf16x8*)(pbase + (kc * 64 + lane) * 8);
      #pragma unroll
      for (int dt = 0; dt < 2; dt++) {
        bf16x8 vf = *(const bf16x8*)(vb + (size_t)(jt * 4 + dt * 2 + kc) * 512 + lane * 8);
        cacc[dt] = __builtin_amdgcn_mfma_f32_16x16x32_bf16(pf, vf, cacc[dt], 0, 0, 0);
      }
    }
  }
  #pragma unroll
  for (int reg = 0; reg < 4; reg++) {
    const float linv = 1.f / l_run[reg];
    const size_t row = (size_t)(b * N_ + i0w + q * 4 + reg);
    #pragma unroll
    for (int dt = 0; dt < 2; dt++)
      ctxo[row * E_ + h * HD_ + dt * 16 + l15] = f2b(cacc[dt][reg] * linv);
  }
}

// ---------------- 4. LayerNorm over E=256; optional bf16 out; optional fused
// pooling weight ew[row] = exp(tanh(dot(o, wp) + bp)) ----------------
__global__ __launch_bounds__(256) void layernorm_kernel(
    const float* __restrict__ t, const float* __restrict__ g,
    const float* __restrict__ be, float* __restrict__ out,
    unsigned short* __restrict__ outb, const float* __restrict__ wp,
    const float* __restrict__ bp, float* __restrict__ ew) {
  const int row = blockIdx.x;
  const int tid = threadIdx.x;
  float v = t[(size_t)row * E_ + tid];
  float s = v, s2 = v * v;
  #pragma unroll
  for (int off = 32; off > 0; off >>= 1) {
    s += __shfl_xor(s, off);
    s2 += __shfl_xor(s2, off);
  }
  __shared__ float sh[8];
  const int wave = tid >> 6, lane = tid & 63;
  if (lane == 0) { sh[wave] = s; sh[4 + wave] = s2; }
  __syncthreads();
  s = sh[0] + sh[1] + sh[2] + sh[3];
  s2 = sh[4] + sh[5] + sh[6] + sh[7];
  float mean = s * (1.f / 256.f);
  float var = s2 * (1.f / 256.f) - mean * mean;
  float inv = rsqrtf(var + 1e-5f);
  float o = (v - mean) * inv * g[tid] + be[tid];
  out[(size_t)row * E_ + tid] = o;
  if (outb) outb[(size_t)row * E_ + tid] = f2b(o);
  if (ew) {
    float d = o * wp[tid];
    #pragma unroll
    for (int off = 32; off > 0; off >>= 1) d += __shfl_xor(d, off);
    __syncthreads();
    if (lane == 0) sh[wave] = d;
    __syncthreads();
    if (tid == 0) {
      float dot = sh[0] + sh[1] + sh[2] + sh[3] + bp[0];
      ew[row] = __expf(tanhf(dot));
    }
  }
}

// ---------------- 5a. pooling partial sums: 32 chunks x 8 batches ----------------
__global__ __launch_bounds__(256) void pool_partial(
    const float* __restrict__ x2, const float* __restrict__ ew,
    float* __restrict__ partial, float* __restrict__ pwsum) {
  const int c = blockIdx.x;   // 0..31
  const int b = blockIdx.y;   // 0..7
  const int tid = threadIdx.x;
  const int r0 = b * N_ + c * 16;
  float acc = 0.f;
  #pragma unroll
  for (int n = 0; n < 16; n++)
    acc += ew[r0 + n] * x2[(size_t)(r0 + n) * E_ + tid];
  partial[(size_t)(b * 32 + c) * E_ + tid] = acc;
  if (tid < 16) {
    float w = ew[r0 + tid];
    #pragma unroll
    for (int off = 1; off < 16; off <<= 1) w += __shfl_xor(w, off);
    if (tid == 0) pwsum[b * 32 + c] = w;
  }
}

// ---------------- 5b. pooling final reduce ----------------
__global__ __launch_bounds__(256) void pool_final(
    const float* __restrict__ partial, const float* __restrict__ pwsum,
    float* __restrict__ out) {
  const int b = blockIdx.x;
  const int tid = threadIdx.x;
  float acc = 0.f, ws = 0.f;
  #pragma unroll
  for (int c = 0; c < 32; c++) acc += partial[(size_t)(b * 32 + c) * E_ + tid];
  #pragma unroll
  for (int c = 0; c < 32; c++) ws += pwsum[b * 32 + c];
  out[b * E_ + tid] = acc / ws;
}

// ---------------- launch ----------------
extern "C" void kernel_launch(void* const* d_in, const int* in_sizes, int n_in,
                              void* d_out, int out_size, void* d_ws, size_t ws_size,
                              hipStream_t stream) {
  (void)in_sizes; (void)n_in; (void)out_size; (void)ws_size;
  const float* x      = (const float*)d_in[0];
  const float* adj    = (const float*)d_in[1];
  const float* emb    = (const float*)d_in[2];
  const float* w_qkv  = (const float*)d_in[3];
  const float* b_qkv  = (const float*)d_in[4];
  const float* w_out  = (const float*)d_in[5];
  const float* b_out  = (const float*)d_in[6];
  const float* w_ff1  = (const float*)d_in[7];
  const float* b_ff1  = (const float*)d_in[8];
  const float* w_ff2  = (const float*)d_in[9];
  const float* b_ff2  = (const float*)d_in[10];
  const float* g1     = (const float*)d_in[11];
  const float* be1    = (const float*)d_in[12];
  const float* g2     = (const float*)d_in[13];
  const float* be2    = (const float*)d_in[14];
  const float* w_pool = (const float*)d_in[15];
  const float* b_pool = (const float*)d_in[16];

  char* ws = (char*)d_ws;
  unsigned int*   bits  = (unsigned int*)ws;                       // 256 KB
  unsigned short* xb    = (unsigned short*)(ws + 262144);          // 2 MB
  unsigned short* qkvb  = (unsigned short*)(ws + 2359296);         // 6 MB (Q rows only used)
  unsigned short* hffb  = xb;                                      // 8 MB reuse (xb+qkvb dead by ff1)
  unsigned short* ctxb  = (unsigned short*)(ws + 8650752);         // 2 MB
  unsigned short* x1b   = (unsigned short*)(ws + 10747904);        // 2 MB
  unsigned short* wqkvb = (unsigned short*)(ws + 12845056);        // 384 KB
  unsigned short* woutb = (unsigned short*)(ws + 13238272);        // 128 KB
  unsigned short* wff1b = (unsigned short*)(ws + 13369344);        // 512 KB
  unsigned short* wff2b = (unsigned short*)(ws + 13893632);        // 512 KB
  unsigned short* vG    = (unsigned short*)(ws + 14417920);        // 2 MB frag-order
  unsigned short* kG    = (unsigned short*)(ws + 16515072);        // 2 MB frag-order
  float*          tbuf  = (float*)(ws + 18612224);                 // 4 MB
  float*          x1    = (float*)(ws + 22806528);                 // 4 MB
  float*          x2    = (float*)(ws + 27000832);                 // 4 MB
  // pooling scratch reuses ctxb region (dead after out-proj gemm)
  float*          ew      = (float*)(ws + 8650752);                // 16 KB
  float*          partial = (float*)(ws + 8650752 + 16384);        // 256 KB
  float*          pwsum   = (float*)(ws + 8650752 + 16384 + 262144);
  float*          outp  = (float*)d_out;

  const int M = B_ * N_;  // 4096

  cvt_all<<<1835008 / 1024, 256, 0, stream>>>(x, w_qkv, w_out, w_ff1, w_ff2,
                                              xb, wqkvb, woutb, wff1b, wff2b);
  topk_kernel<<<B_ * N_, 256, 0, stream>>>(adj, bits);
  gemm_mfma<<<dim3(768 / 64, M / 64), 256, 0, stream>>>(
      xb, wqkvb, b_qkv, nullptr, qkvb, kG, vG, M, 768, E_, 2);
  attn_mfma<<<B_ * H_ * (N_ / 64), 256, 0, stream>>>(qkvb, kG, vG, bits, emb, ctxb);
  gemm_mfma<<<dim3(E_ / 64, M / 64), 256, 0, stream>>>(
      ctxb, woutb, b_out, x, tbuf, nullptr, nullptr, M, E_, E_, 0);
  layernorm_kernel<<<M, 256, 0, stream>>>(tbuf, g1, be1, x1, x1b,
                                          nullptr, nullptr, nullptr);
  gemm_mfma<<<dim3(1024 / 64, M / 64), 256, 0, stream>>>(
      x1b, wff1b, b_ff1, nullptr, hffb, nullptr, nullptr, M, 1024, E_, 1 | 2);
  gemm_mfma<<<dim3(E_ / 64, M / 64), 256, 0, stream>>>(
      hffb, wff2b, b_ff2, x1, tbuf, nullptr, nullptr, M, E_, 1024, 0);
  layernorm_kernel<<<M, 256, 0, stream>>>(tbuf, g2, be2, x2, nullptr,
                                          w_pool, b_pool, ew);
  pool_partial<<<dim3(32, 8), 256, 0, stream>>>(x2, ew, partial, pwsum);
  pool_final<<<B_, 256, 0, stream>>>(partial, pwsum, outp);
}